// Round 8
// baseline (3015.714 us; speedup 1.0000x reference)
//
#include <hip/hip_runtime.h>
#include <hip/hip_bf16.h>
#include <hip/hip_fp8.h>
#include <cstdint>
#include <cstddef>

// VanillaRNN: h_{t+1} = tanh(x_t @ Whx + h_t @ Whh + bh), p = h_T @ Wph + bp
// B=256, T=1024, D=64, H=512, C=10.
//
// R7 vs R6 (R6: 2747us — fused path fired but consumer slowed to 6340cyc/step
// vs R3's 3970. Suspects: per-wave gate (8 waves x device-atomic +
// full __threadfence incl. buffer_wbl2+buffer_inv every 8 steps) and
// __launch_bounds__(512,1) codegen):
//  - Gate restructured: ONLY wave0-lane0 spins (device-scope atomicAdd) at the
//    BOTTOM of iteration t for chunk(t+2); wave0 alone issues an ACQUIRE-only
//    fence (buffer_inv, no wbl2). The existing per-step __syncthreads orders
//    it before all waves' U(t+2) prefetch (L1 is per-CU, L2 per-XCD — shared
//    by the block, so one wave's invalidate suffices). Waves 1..7 run a loop
//    byte-identical to R3's consumer.
//  - __launch_bounds__ back to (512,2) (every fast round used it). To fit the
//    256-reg cap, phase 1 (t<8, x@Whx inline) rebuilds Whx frags from global
//    (L2-hot) per step instead of keeping them resident.
// Unchanged from R6: R3-exact consumer split/chains (KS 10/2/4, C || C2),
// U covers t in [8,1024) (fits ws=256MiB with 8KB flags at head), producers
// = 2032 blocks on the other 240 CUs (SMEM 92.7KB -> 1 block/CU everywhere).

#define T_SEQ   1024
#define D_IN    64
#define H_DIM   512
#define NB      16
#define NBLK    16
#define NTW     4            // N-tiles (16 cols) per wave; wave owns 64 cols
#define KS_F16  10           // f16 K-steps: h[0,320)  (R3 split)
#define KS_REG8 2            // fp8 K-steps with reg weights: h[320,384)
#define KS_LDS8 4            // fp8 K-steps with LDS weights: h[384,512)
#define HSPLIT  320          // h cols >= HSPLIT stored fp8
#define APITCH  848          // bytes per A row: 640 f16 + 192 fp8 + 16 pad
#define FP8OFF  640
#define ABUF_BYTES (2 * NB * APITCH)              // 27136
#define WWAVE_BYTES (KS_LDS8 * 2 * 1024)          // 8192
#define WLDS_BYTES (8 * WWAVE_BYTES)              // 65536
#define SMEM_TOTAL (ABUF_BYTES + WLDS_BYTES)      // 92672 (>80K -> 1 block/CU)
#define WSCALE  256.0f
#define HSCALE  128.0f
#define UNSCALE (1.0f / 32768.0f)
#define T0      8            // steps computed inline by consumer (no U)
#define TT      8            // t-steps per producer block / gate chunk
#define NCHUNK  ((T_SEQ - T0) / TT)               // 127
#define NPROD   (NBLK * NCHUNK)                   // 2032
#define UOFF    8192         // flags occupy d_ws[0..8192); U follows
#define U2_BYTES ((size_t)(T_SEQ - T0) * NBLK * 512 * 32)  // 266,338,304
#define WS_NEED  (UOFF + U2_BYTES)                          // 266,346,496

typedef __attribute__((ext_vector_type(8))) short  short8;
typedef __attribute__((ext_vector_type(4))) short  short4v;
typedef __attribute__((ext_vector_type(4))) float  f32x4;
typedef __attribute__((ext_vector_type(4))) unsigned int uint4v;
typedef __attribute__((ext_vector_type(2))) unsigned int uint2v;

static __device__ __forceinline__ short f16b(float v) {
  return __builtin_bit_cast(short, (_Float16)v);
}
static __device__ __forceinline__ short bf16b(float v) {
  return __builtin_bit_cast(short, __float2bfloat16(v));
}
static __device__ __forceinline__ float f16f(unsigned short u) {
  return (float)__builtin_bit_cast(_Float16, (short)u);
}
static __device__ __forceinline__ unsigned int pk2h(float a, float b) {
#if defined(__has_builtin) && __has_builtin(__builtin_amdgcn_cvt_pkrtz)
  return __builtin_bit_cast(unsigned int, __builtin_amdgcn_cvt_pkrtz(a, b));
#else
  return (unsigned int)(unsigned short)f16b(a) |
         ((unsigned int)(unsigned short)f16b(b) << 16);
#endif
}
static __device__ __forceinline__ float fast_tanh(float x) {
  x = fminf(20.f, fmaxf(-20.f, x));
  const float t = __builtin_amdgcn_exp2f(x * 2.885390081777927f); // 2*log2(e)
  return (t - 1.f) * __builtin_amdgcn_rcpf(t + 1.f);
}
static __device__ __forceinline__ unsigned char f32_to_fp8(float v) {
#if defined(__has_builtin) && __has_builtin(__builtin_amdgcn_cvt_pk_fp8_f32)
  const int r = __builtin_amdgcn_cvt_pk_fp8_f32(v, v, 0, false);
  return (unsigned char)(r & 0xff);
#else
  __hip_fp8_e4m3 f(v);
  return (unsigned char)f.__x;
#endif
}
static __device__ __forceinline__ unsigned int pk4fp8(float a, float b, float c, float d) {
#if defined(__has_builtin) && __has_builtin(__builtin_amdgcn_cvt_pk_fp8_f32)
  int r = __builtin_amdgcn_cvt_pk_fp8_f32(a, b, 0, false);
  r = __builtin_amdgcn_cvt_pk_fp8_f32(c, d, r, true);
  return (unsigned int)r;
#else
  return (unsigned int)f32_to_fp8(a) | ((unsigned int)f32_to_fp8(b) << 8) |
         ((unsigned int)f32_to_fp8(c) << 16) | ((unsigned int)f32_to_fp8(d) << 24);
#endif
}
static __device__ __forceinline__ float fp8_to_f32(unsigned char b) {
  __hip_fp8_e4m3 f;
  f.__x = (__hip_fp8_storage_t)b;
  return (float)f;
}
static __device__ __forceinline__ void acquire_fence_agent() {
#if defined(__has_builtin) && __has_builtin(__builtin_amdgcn_fence)
  __builtin_amdgcn_fence(__ATOMIC_ACQUIRE, "agent");
#else
  __threadfence();
#endif
}

// ===================== producer: U(t) = x_t@Whx + bh, t in [8,1024) =========
// U slot: thread (wg, tid) at step t owns 32 B at (((t-8)*NBLK+wg)*512+tid)*32.
static __device__ __forceinline__ void producer_body(
    int pid, const float* __restrict__ x, const float* __restrict__ Whx,
    const float* __restrict__ bh, char* __restrict__ U,
    unsigned int* __restrict__ flags)
{
  const int wg = pid & (NBLK - 1);
  const int tc = pid >> 4;            // chunk 0..126
  const int tid  = threadIdx.x;
  const int lane = tid & 63;
  const int w    = tid >> 6;
  const int n16  = lane & 15;
  const int kq   = lane >> 4;
  const int cwave = w * 64;

  short8 wa[2][NTW];
  #pragma unroll
  for (int s = 0; s < 2; ++s) {
    #pragma unroll
    for (int nt = 0; nt < NTW; ++nt) {
      const int c = cwave + nt * 16 + n16;
      short8 f;
      #pragma unroll
      for (int j = 0; j < 8; ++j)
        f[j] = f16b(Whx[(size_t)(s * 32 + kq * 8 + j) * H_DIM + c]);
      wa[s][nt] = f;
    }
  }
  f32x4 bb[NTW];
  #pragma unroll
  for (int nt = 0; nt < NTW; ++nt) {
    #pragma unroll
    for (int i = 0; i < 4; ++i) bb[nt][i] = bh[cwave + nt * 16 + kq * 4 + i];
  }

  const int b = wg * NB + n16;
  for (int tt = 0; tt < TT; ++tt) {
    const int t = T0 + tc * TT + tt;
    short8 xb[2];
    #pragma unroll
    for (int s = 0; s < 2; ++s) {
      const float* px = x + ((size_t)b * T_SEQ + t) * D_IN + s * 32 + kq * 8;
      const f32x4 v0 = *(const f32x4*)px;
      const f32x4 v1 = *(const f32x4*)(px + 4);
      short8 f;
      f[0]=f16b(v0.x); f[1]=f16b(v0.y); f[2]=f16b(v0.z); f[3]=f16b(v0.w);
      f[4]=f16b(v1.x); f[5]=f16b(v1.y); f[6]=f16b(v1.z); f[7]=f16b(v1.w);
      xb[s] = f;
    }
    f32x4 D[NTW];
    #pragma unroll
    for (int nt = 0; nt < NTW; ++nt) {
      D[nt] = bb[nt];
      D[nt] = __builtin_amdgcn_mfma_f32_16x16x32_f16(wa[0][nt], xb[0], D[nt], 0, 0, 0);
      D[nt] = __builtin_amdgcn_mfma_f32_16x16x32_f16(wa[1][nt], xb[1], D[nt], 0, 0, 0);
    }
    uint4v o0, o1;
    o0.x = pk2h(D[0][0], D[0][1]); o0.y = pk2h(D[0][2], D[0][3]);
    o0.z = pk2h(D[1][0], D[1][1]); o0.w = pk2h(D[1][2], D[1][3]);
    o1.x = pk2h(D[2][0], D[2][1]); o1.y = pk2h(D[2][2], D[2][3]);
    o1.z = pk2h(D[3][0], D[3][1]); o1.w = pk2h(D[3][2], D[3][3]);
    char* dst = U + (((size_t)(t - T0) * NBLK + wg) * 512 + tid) * 32;
    *(uint4v*)dst = o0;
    *(uint4v*)(dst + 16) = o1;
  }

  __syncthreads();                       // drain all waves' stores
  if (threadIdx.x == 0) {
    __threadfence();                     // release: publish U device-wide
    atomicExch(&flags[wg * 128 + tc], 1u);
  }
}

// ===================== consumer: the recurrence for one wg ===================
static __device__ __forceinline__ void consumer_body(
    int wg, const float* __restrict__ x, const float* __restrict__ Whx,
    const float* __restrict__ Whh, const float* __restrict__ Wph,
    const float* __restrict__ bh, const float* __restrict__ bp,
    const char* __restrict__ U, unsigned int* __restrict__ flags,
    float* __restrict__ out)
{
  const int tid  = threadIdx.x;
  const int lane = tid & 63;
  const int w    = tid >> 6;
  const int n16  = lane & 15;
  const int kq   = lane >> 4;
  const int rbase = wg * NB;
  const int cwave = w * 64;

  extern __shared__ char smem[];
  char* Ab  = smem;                                  // [2][NB][APITCH]
  char* Wlw = smem + ABUF_BYTES + w * WWAVE_BYTES;   // this wave's LDS fp8 wts

  // -------- preload: f16 weight A-frags (h-k in [0,320)), 40 frags (R3)
  short8 wr[KS_F16][NTW];
  #pragma unroll
  for (int s = 0; s < KS_F16; ++s) {
    #pragma unroll
    for (int nt = 0; nt < NTW; ++nt) {
      const int c = cwave + nt * 16 + n16;
      short8 f;
      #pragma unroll
      for (int j = 0; j < 8; ++j)
        f[j] = f16b(Whh[(size_t)(s * 32 + kq * 8 + j) * H_DIM + c]);
      wr[s][nt] = f;
    }
  }
  // -------- preload: reg-resident fp8 weight A-frags (h-k in [320,384)) (R3)
  long long wf8[KS_REG8][NTW];
  #pragma unroll
  for (int s = 0; s < KS_REG8; ++s) {
    #pragma unroll
    for (int nt = 0; nt < NTW; ++nt) {
      const int c  = cwave + nt * 16 + n16;
      const int k0 = (KS_F16 + s) * 32 + kq * 8;
      unsigned int lo = 0, hi = 0;
      #pragma unroll
      for (int bi = 0; bi < 4; ++bi) {
        lo |= ((unsigned int)f32_to_fp8(Whh[(size_t)(k0 + bi) * H_DIM + c] * WSCALE)) << (8 * bi);
        hi |= ((unsigned int)f32_to_fp8(Whh[(size_t)(k0 + 4 + bi) * H_DIM + c] * WSCALE)) << (8 * bi);
      }
      wf8[s][nt] = (long long)(((unsigned long long)hi << 32) | lo);
    }
  }
  // -------- preload: LDS fp8 weight A-frags (h-k in [384,512)) (R3)
  for (int sl = 0; sl < KS_LDS8; ++sl) {
    for (int half = 0; half < 2; ++half) {
      const int k0 = (KS_F16 + KS_REG8 + sl) * 32 + kq * 8;
      unsigned int bqq[4];
      #pragma unroll
      for (int hh = 0; hh < 2; ++hh) {
        const int c = cwave + (2 * half + hh) * 16 + n16;
        #pragma unroll
        for (int u = 0; u < 2; ++u) {
          unsigned int acc = 0;
          #pragma unroll
          for (int bi = 0; bi < 4; ++bi)
            acc |= ((unsigned int)f32_to_fp8(Whh[(size_t)(k0 + u * 4 + bi) * H_DIM + c] * WSCALE)) << (8 * bi);
          bqq[hh * 2 + u] = acc;
        }
      }
      uint4v pk; pk.x = bqq[0]; pk.y = bqq[1]; pk.z = bqq[2]; pk.w = bqq[3];
      *(uint4v*)(Wlw + (size_t)(sl * 2 + half) * 1024 + lane * 16) = pk;
    }
  }

  // -------- prologue: zero both A buffers (h_0 = 0)
  for (int i = tid; i < ABUF_BYTES / 4; i += 512) ((int*)Ab)[i] = 0;

  f32x4 C[NTW], C2[NTW];

  // =========== phase 1: t in [0,8) — x@Whx inline, Whx frags rebuilt
  // from global each step (L2-hot; keeps regs within the (512,2) cap) ========
  for (int t = 0; t < T0; ++t) {
    __syncthreads();
    char* Ac = Ab + (t & 1) * (NB * APITCH);
    char* An = Ab + ((t + 1) & 1) * (NB * APITCH);

    short8 hb = *(const short8*)(Ac + n16 * APITCH + 0 * 64 + kq * 16);

    // x_t B-frags (this wg's 16 rows), fp32 -> f16
    short8 xb[2];
    #pragma unroll
    for (int s = 0; s < 2; ++s) {
      const float* px = x + ((size_t)(rbase + n16) * T_SEQ + t) * D_IN + s * 32 + kq * 8;
      const f32x4 v0 = *(const f32x4*)px;
      const f32x4 v1 = *(const f32x4*)(px + 4);
      short8 f;
      f[0]=f16b(v0.x); f[1]=f16b(v0.y); f[2]=f16b(v0.z); f[3]=f16b(v0.w);
      f[4]=f16b(v1.x); f[5]=f16b(v1.y); f[6]=f16b(v1.z); f[7]=f16b(v1.w);
      xb[s] = f;
    }
    // C init = bh; then C += Whx^T-frags (rebuilt) @ x
    #pragma unroll
    for (int nt = 0; nt < NTW; ++nt) {
      #pragma unroll
      for (int i = 0; i < 4; ++i)
        C[nt][i] = bh[cwave + nt * 16 + kq * 4 + i];
      C2[nt] = (f32x4){0.f, 0.f, 0.f, 0.f};
    }
    #pragma unroll
    for (int s = 0; s < 2; ++s) {
      #pragma unroll
      for (int nt = 0; nt < NTW; ++nt) {
        const int c = cwave + nt * 16 + n16;
        short8 f;
        #pragma unroll
        for (int j = 0; j < 8; ++j)
          f[j] = f16b(Whx[(size_t)(s * 32 + kq * 8 + j) * H_DIM + c]);
        C[nt] = __builtin_amdgcn_mfma_f32_16x16x32_f16(f, xb[s], C[nt], 0, 0, 0);
      }
    }

    #pragma unroll
    for (int s = 0; s < KS_F16; ++s) {
      const short8 a = hb;
      if (s + 1 < KS_F16)
        hb = *(const short8*)(Ac + n16 * APITCH + (s + 1) * 64 + kq * 16);
      #pragma unroll
      for (int nt = 0; nt < NTW; ++nt)
        C[nt] = __builtin_amdgcn_mfma_f32_16x16x32_f16(wr[s][nt], a, C[nt], 0, 0, 0);
    }
    #pragma unroll
    for (int s = 0; s < KS_REG8; ++s) {
      const long long h8 = *(const long long*)(Ac + n16 * APITCH + FP8OFF + s * 32 + kq * 8);
      #pragma unroll
      for (int nt = 0; nt < NTW; ++nt)
        C2[nt] = __builtin_amdgcn_mfma_f32_16x16x32_fp8_fp8(wf8[s][nt], h8, C2[nt], 0, 0, 0);
    }
    #pragma unroll
    for (int sl = 0; sl < KS_LDS8; ++sl) {
      const long long h8 = *(const long long*)(Ac + n16 * APITCH + FP8OFF + (KS_REG8 + sl) * 32 + kq * 8);
      const uint4v q0 = *(const uint4v*)(Wlw + (size_t)(sl * 2 + 0) * 1024 + lane * 16);
      const uint4v q1 = *(const uint4v*)(Wlw + (size_t)(sl * 2 + 1) * 1024 + lane * 16);
      const long long w0 = (long long)(((unsigned long long)q0.y << 32) | q0.x);
      const long long w1 = (long long)(((unsigned long long)q0.w << 32) | q0.z);
      const long long w2 = (long long)(((unsigned long long)q1.y << 32) | q1.x);
      const long long w3 = (long long)(((unsigned long long)q1.w << 32) | q1.z);
      C2[0] = __builtin_amdgcn_mfma_f32_16x16x32_fp8_fp8(w0, h8, C2[0], 0, 0, 0);
      C2[1] = __builtin_amdgcn_mfma_f32_16x16x32_fp8_fp8(w1, h8, C2[1], 0, 0, 0);
      C2[2] = __builtin_amdgcn_mfma_f32_16x16x32_fp8_fp8(w2, h8, C2[2], 0, 0, 0);
      C2[3] = __builtin_amdgcn_mfma_f32_16x16x32_fp8_fp8(w3, h8, C2[3], 0, 0, 0);
    }

    char* drow = An + n16 * APITCH;
    if (cwave < HSPLIT) {
      #pragma unroll
      for (int nt = 0; nt < NTW; ++nt) {
        const int c0 = cwave + nt * 16 + kq * 4;
        float v0 = fast_tanh(fmaf(C2[nt][0], UNSCALE, C[nt][0]));
        float v1 = fast_tanh(fmaf(C2[nt][1], UNSCALE, C[nt][1]));
        float v2 = fast_tanh(fmaf(C2[nt][2], UNSCALE, C[nt][2]));
        float v3 = fast_tanh(fmaf(C2[nt][3], UNSCALE, C[nt][3]));
        uint2v o; o.x = pk2h(v0, v1); o.y = pk2h(v2, v3);
        *(uint2v*)(drow + c0 * 2) = o;
      }
    } else {
      #pragma unroll
      for (int nt = 0; nt < NTW; ++nt) {
        const int c0 = cwave + nt * 16 + kq * 4;
        float v0 = fast_tanh(fmaf(C2[nt][0], UNSCALE, C[nt][0]));
        float v1 = fast_tanh(fmaf(C2[nt][1], UNSCALE, C[nt][1]));
        float v2 = fast_tanh(fmaf(C2[nt][2], UNSCALE, C[nt][2]));
        float v3 = fast_tanh(fmaf(C2[nt][3], UNSCALE, C[nt][3]));
        *(unsigned int*)(drow + FP8OFF + (c0 - HSPLIT)) =
            pk4fp8(v0 * HSCALE, v1 * HSCALE, v2 * HSCALE, v3 * HSCALE);
      }
    }
  }

  // gate chunk 0 (wave0 only) -> barrier orders it for all waves' U(8) load
  if (w == 0) {
    if (lane == 0) {
      while (atomicAdd(&flags[wg * 128 + 0], 0u) == 0u) { }
    }
    acquire_fence_agent();
  }
  __syncthreads();
  uint4v Upf0, Upf1;
  {
    const char* up = U + (((size_t)0 * NBLK + wg) * 512 + tid) * 32;
    Upf0 = *(const uint4v*)up;
    Upf1 = *(const uint4v*)(up + 16);
  }

  // =========== phase 2: t in [8,1024) — exact R3 body; wave0-only gating ====
  for (int t = T0; t < T_SEQ; ++t) {
    __syncthreads();
    char* Ac = Ab + (t & 1) * (NB * APITCH);
    char* An = Ab + ((t + 1) & 1) * (NB * APITCH);

    short8 hb = *(const short8*)(Ac + n16 * APITCH + 0 * 64 + kq * 16);

    // C-init from prefetched U
    C[0][0]=f16f(Upf0.x&0xffff); C[0][1]=f16f(Upf0.x>>16);
    C[0][2]=f16f(Upf0.y&0xffff); C[0][3]=f16f(Upf0.y>>16);
    C[1][0]=f16f(Upf0.z&0xffff); C[1][1]=f16f(Upf0.z>>16);
    C[1][2]=f16f(Upf0.w&0xffff); C[1][3]=f16f(Upf0.w>>16);
    C[2][0]=f16f(Upf1.x&0xffff); C[2][1]=f16f(Upf1.x>>16);
    C[2][2]=f16f(Upf1.y&0xffff); C[2][3]=f16f(Upf1.y>>16);
    C[3][0]=f16f(Upf1.z&0xffff); C[3][1]=f16f(Upf1.z>>16);
    C[3][2]=f16f(Upf1.w&0xffff); C[3][3]=f16f(Upf1.w>>16);
    #pragma unroll
    for (int nt = 0; nt < NTW; ++nt) C2[nt] = (f32x4){0.f, 0.f, 0.f, 0.f};

    // prefetch U(t+1) — its chunk was gated at the bottom of iteration t-1
    {
      const int t1 = (t + 1 < T_SEQ) ? (t + 1) : (T_SEQ - 1);
      const char* up = U + (((size_t)(t1 - T0) * NBLK + wg) * 512 + tid) * 32;
      Upf0 = *(const uint4v*)up;
      Upf1 = *(const uint4v*)(up + 16);
    }

    // f16 phase (C-chain)
    #pragma unroll
    for (int s = 0; s < KS_F16; ++s) {
      const short8 a = hb;
      if (s + 1 < KS_F16)
        hb = *(const short8*)(Ac + n16 * APITCH + (s + 1) * 64 + kq * 16);
      #pragma unroll
      for (int nt = 0; nt < NTW; ++nt)
        C[nt] = __builtin_amdgcn_mfma_f32_16x16x32_f16(wr[s][nt], a, C[nt], 0, 0, 0);
    }
    // fp8 phase (independent C2-chain)
    #pragma unroll
    for (int s = 0; s < KS_REG8; ++s) {
      const long long h8 = *(const long long*)(Ac + n16 * APITCH + FP8OFF + s * 32 + kq * 8);
      #pragma unroll
      for (int nt = 0; nt < NTW; ++nt)
        C2[nt] = __builtin_amdgcn_mfma_f32_16x16x32_fp8_fp8(wf8[s][nt], h8, C2[nt], 0, 0, 0);
    }
    #pragma unroll
    for (int sl = 0; sl < KS_LDS8; ++sl) {
      const long long h8 = *(const long long*)(Ac + n16 * APITCH + FP8OFF + (KS_REG8 + sl) * 32 + kq * 8);
      const uint4v q0 = *(const uint4v*)(Wlw + (size_t)(sl * 2 + 0) * 1024 + lane * 16);
      const uint4v q1 = *(const uint4v*)(Wlw + (size_t)(sl * 2 + 1) * 1024 + lane * 16);
      const long long w0 = (long long)(((unsigned long long)q0.y << 32) | q0.x);
      const long long w1 = (long long)(((unsigned long long)q0.w << 32) | q0.z);
      const long long w2 = (long long)(((unsigned long long)q1.y << 32) | q1.x);
      const long long w3 = (long long)(((unsigned long long)q1.w << 32) | q1.z);
      C2[0] = __builtin_amdgcn_mfma_f32_16x16x32_fp8_fp8(w0, h8, C2[0], 0, 0, 0);
      C2[1] = __builtin_amdgcn_mfma_f32_16x16x32_fp8_fp8(w1, h8, C2[1], 0, 0, 0);
      C2[2] = __builtin_amdgcn_mfma_f32_16x16x32_fp8_fp8(w2, h8, C2[2], 0, 0, 0);
      C2[3] = __builtin_amdgcn_mfma_f32_16x16x32_fp8_fp8(w3, h8, C2[3], 0, 0, 0);
    }

    // epilogue: fold + tanh + packed store
    char* drow = An + n16 * APITCH;
    if (cwave < HSPLIT) {
      #pragma unroll
      for (int nt = 0; nt < NTW; ++nt) {
        const int c0 = cwave + nt * 16 + kq * 4;
        float v0 = fast_tanh(fmaf(C2[nt][0], UNSCALE, C[nt][0]));
        float v1 = fast_tanh(fmaf(C2[nt][1], UNSCALE, C[nt][1]));
        float v2 = fast_tanh(fmaf(C2[nt][2], UNSCALE, C[nt][2]));
        float v3 = fast_tanh(fmaf(C2[nt][3], UNSCALE, C[nt][3]));
        uint2v o; o.x = pk2h(v0, v1); o.y = pk2h(v2, v3);
        *(uint2v*)(drow + c0 * 2) = o;
      }
    } else {
      #pragma unroll
      for (int nt = 0; nt < NTW; ++nt) {
        const int c0 = cwave + nt * 16 + kq * 4;
        float v0 = fast_tanh(fmaf(C2[nt][0], UNSCALE, C[nt][0]));
        float v1 = fast_tanh(fmaf(C2[nt][1], UNSCALE, C[nt][1]));
        float v2 = fast_tanh(fmaf(C2[nt][2], UNSCALE, C[nt][2]));
        float v3 = fast_tanh(fmaf(C2[nt][3], UNSCALE, C[nt][3]));
        *(unsigned int*)(drow + FP8OFF + (c0 - HSPLIT)) =
            pk4fp8(v0 * HSCALE, v1 * HSCALE, v2 * HSCALE, v3 * HSCALE);
      }
    }

    // wave0-only gate for the chunk first needed at iteration t+1's prefetch
    // (t2 = t+2). Ordered for all waves by the barrier at the next loop top.
    {
      const int t2 = t + 2;
      if (t2 < T_SEQ && (t2 & (TT - 1)) == 0) {
        if (w == 0) {
          if (lane == 0) {
            while (atomicAdd(&flags[wg * 128 + ((t2 - T0) >> 3)], 0u) == 0u) { }
          }
          acquire_fence_agent();
        }
      }
    }
  }

  __syncthreads();
  // h_T in buffer 0 (T even). Projection: 16 rows x 10 classes.
  if (tid < NB * 10) {
    const int r = tid / 10, c = tid % 10;
    const char* row = Ab + r * APITCH;
    float acc = bp[c];
    #pragma unroll 8
    for (int k = 0; k < HSPLIT; ++k)
      acc += f16f(*(const unsigned short*)(row + k * 2)) * Wph[k * 10 + c];
    #pragma unroll 8
    for (int k = HSPLIT; k < H_DIM; ++k)
      acc += fp8_to_f32((unsigned char)row[FP8OFF + (k - HSPLIT)]) * (1.f / HSCALE) * Wph[k * 10 + c];
    out[(size_t)(rbase + r) * 10 + c] = acc;
  }
}

// ===================== fused kernel =========================================
// blockIdx < 16: consumer (gated). blockIdx >= 16: producer pid = blockIdx-16.
__global__ __launch_bounds__(512, 2)
void VanillaRNN_70025146794452_kernel(
    const float* __restrict__ x, const float* __restrict__ Whx,
    const float* __restrict__ Whh, const float* __restrict__ Wph,
    const float* __restrict__ bh, const float* __restrict__ bp,
    char* __restrict__ U, unsigned int* __restrict__ flags,
    float* __restrict__ out)
{
  if (blockIdx.x < NBLK)
    consumer_body(blockIdx.x, x, Whx, Whh, Wph, bh, bp, U, flags, out);
  else
    producer_body(blockIdx.x - NBLK, x, Whx, bh, U, flags);
}

// ============================ fallback (R2 verbatim, 2833us) =================
#define FB_APITCH  1040
#define FB_FP8OFF  768
#define FB_ABUF    (2 * NB * FB_APITCH)
#define FB_WWAVE   (6 * 2 * 1024)
#define FB_SMEM    (FB_ABUF + 8 * FB_WWAVE)       // 131584

__global__ __launch_bounds__(512, 2)
void rnn_fallback_kernel(
    const float* __restrict__ x, const float* __restrict__ Whx,
    const float* __restrict__ Whh, const float* __restrict__ Wph,
    const float* __restrict__ bh, const float* __restrict__ bp,
    float* __restrict__ out)
{
  const int tid = threadIdx.x, lane = tid & 63, w = tid >> 6;
  const int n16 = lane & 15, kq = lane >> 4;
  const int rbase = blockIdx.x * NB, cwave = w * 64;
  extern __shared__ char smem[];
  char* Ab  = smem;
  char* Wlw = smem + FB_ABUF + w * FB_WWAVE;

  short8 wr[12 * 4];
  #pragma unroll
  for (int s = 0; s < 12; ++s)
    #pragma unroll
    for (int nt = 0; nt < 4; ++nt) {
      const int c = cwave + nt * 16 + n16, k0 = s * 32 + kq * 8;
      short8 f;
      #pragma unroll
      for (int j = 0; j < 8; ++j) {
        const int k = k0 + j;
        const float* src = (k < D_IN) ? (Whx + (size_t)k * H_DIM + c)
                                      : (Whh + (size_t)(k - D_IN) * H_DIM + c);
        f[j] = bf16b(*src);
      }
      wr[s * 4 + nt] = f;
    }
  for (int s = 0; s < 6; ++s)
    for (int pp = 0; pp < 2; ++pp) {
      const int k0 = (12 + s) * 32 + kq * 8;
      unsigned int bq[4];
      #pragma unroll
      for (int half = 0; half < 2; ++half) {
        const int c = cwave + (2 * pp + half) * 16 + n16;
        #pragma unroll
        for (int u = 0; u < 2; ++u) {
          unsigned int acc = 0;
          #pragma unroll
          for (int bi = 0; bi < 4; ++bi)
            acc |= ((unsigned int)f32_to_fp8(Whh[(size_t)(k0 + u * 4 + bi - D_IN) * H_DIM + c] * WSCALE)) << (8 * bi);
          bq[half * 2 + u] = acc;
        }
      }
      uint4v pk; pk.x = bq[0]; pk.y = bq[1]; pk.z = bq[2]; pk.w = bq[3];
      *(uint4v*)(Wlw + (size_t)(s * 2 + pp) * 1024 + lane * 16) = pk;
    }
  float bhreg[4];
  #pragma unroll
  for (int nt = 0; nt < 4; ++nt) bhreg[nt] = bh[cwave + nt * 16 + n16];
  for (int i = tid; i < FB_ABUF / 4; i += 512) ((int*)Ab)[i] = 0;
  const int xr = (tid >> 4) & 15, xc4 = (tid & 15) * 4;
  if (tid < 256) {
    const f32x4 xv = *(const f32x4*)(x + ((size_t)(rbase + xr) * T_SEQ) * D_IN + xc4);
    short4v s4; s4[0]=bf16b(xv.x); s4[1]=bf16b(xv.y); s4[2]=bf16b(xv.z); s4[3]=bf16b(xv.w);
    *(short4v*)(Ab + xr * FB_APITCH + xc4 * 2) = s4;
  }
  f32x4 C[4], C2[4];
  for (int t = 0; t < T_SEQ; ++t) {
    __syncthreads();
    char* Ac = Ab + (t & 1) * (NB * FB_APITCH);
    char* An = Ab + ((t + 1) & 1) * (NB * FB_APITCH);
    const int t1 = (t + 1 < T_SEQ) ? (t + 1) : (T_SEQ - 1);
    f32x4 xv;
    if (tid < 256)
      xv = *(const f32x4*)(x + ((size_t)(rbase + xr) * T_SEQ + t1) * D_IN + xc4);
    #pragma unroll
    for (int nt = 0; nt < 4; ++nt) {
      C[nt] = (f32x4){0.f,0.f,0.f,0.f}; C2[nt] = (f32x4){0.f,0.f,0.f,0.f};
    }
    #pragma unroll
    for (int s = 0; s < 12; ++s) {
      const short8 a = *(const short8*)(Ac + n16 * FB_APITCH + s * 64 + kq * 16);
      #pragma unroll
      for (int nt = 0; nt < 4; ++nt)
        C[nt] = __builtin_amdgcn_mfma_f32_16x16x32_bf16(a, wr[s * 4 + nt], C[nt], 0, 0, 0);
    }
    #pragma unroll
    for (int s = 0; s < 6; ++s) {
      const long long a8 = *(const long long*)(Ac + n16 * FB_APITCH + FB_FP8OFF + s * 32 + kq * 8);
      #pragma unroll
      for (int pp = 0; pp < 2; ++pp) {
        const uint4v q = *(const uint4v*)(Wlw + (size_t)(s * 2 + pp) * 1024 + lane * 16);
        const long long b0 = (long long)(((unsigned long long)q.y << 32) | q.x);
        const long long b1 = (long long)(((unsigned long long)q.w << 32) | q.z);
        C2[2*pp]   = __builtin_amdgcn_mfma_f32_16x16x32_fp8_fp8(a8, b0, C2[2*pp],   0, 0, 0);
        C2[2*pp+1] = __builtin_amdgcn_mfma_f32_16x16x32_fp8_fp8(a8, b1, C2[2*pp+1], 0, 0, 0);
      }
    }
    if (tid < 256) {
      short4v s4; s4[0]=bf16b(xv.x); s4[1]=bf16b(xv.y); s4[2]=bf16b(xv.z); s4[3]=bf16b(xv.w);
      *(short4v*)(An + xr * FB_APITCH + xc4 * 2) = s4;
    }
    const int row0 = kq * 4;
    #pragma unroll
    for (int nt = 0; nt < 4; ++nt) {
      const int cbase = cwave + nt * 16;
      #pragma unroll
      for (int i = 0; i < 4; ++i) {
        const float v = fast_tanh(fmaf(C2[nt][i], UNSCALE, C[nt][i]) + bhreg[nt]);
        char* dst = An + (row0 + i) * FB_APITCH;
        if (cbase < 320) *(short*)(dst + 128 + (cbase + n16) * 2) = bf16b(v);
        else dst[FB_FP8OFF + (cbase + n16 - 320)] = f32_to_fp8(v * HSCALE);
      }
    }
  }
  __syncthreads();
  if (tid < NB * 10) {
    const int r = tid / 10, c = tid % 10;
    const char* row = Ab + r * FB_APITCH;
    float acc = bp[c];
    #pragma unroll 8
    for (int k = 0; k < 320; ++k) {
      const __hip_bfloat16 hb = __builtin_bit_cast(__hip_bfloat16, *(const short*)(row + 128 + k * 2));
      acc += __bfloat162float(hb) * Wph[k * 10 + c];
    }
    #pragma unroll 8
    for (int k = 320; k < H_DIM; ++k)
      acc += fp8_to_f32((unsigned char)row[FB_FP8OFF + (k - 320)]) * (1.f / HSCALE) * Wph[k * 10 + c];
    out[(size_t)(rbase + r) * 10 + c] = acc;
  }
}

extern "C" void kernel_launch(void* const* d_in, const int* in_sizes, int n_in,
                              void* d_out, int out_size, void* d_ws, size_t ws_size,
                              hipStream_t stream) {
  const float* x   = (const float*)d_in[0];
  const float* Whx = (const float*)d_in[1];
  const float* Whh = (const float*)d_in[2];
  const float* Wph = (const float*)d_in[3];
  const float* bh  = (const float*)d_in[4];
  const float* bp  = (const float*)d_in[5];
  float* out = (float*)d_out;

  if (ws_size >= WS_NEED) {
    unsigned int* flags = (unsigned int*)d_ws;      // [16][128], first 8KB
    char* U = (char*)d_ws + UOFF;                   // t in [8,1024)
    (void)hipFuncSetAttribute((const void*)VanillaRNN_70025146794452_kernel,
                              hipFuncAttributeMaxDynamicSharedMemorySize, SMEM_TOTAL);
    (void)hipMemsetAsync(flags, 0, UOFF, stream);
    VanillaRNN_70025146794452_kernel<<<dim3(NBLK + NPROD), dim3(512), SMEM_TOTAL, stream>>>(
        x, Whx, Whh, Wph, bh, bp, U, flags, out);
  } else {
    (void)hipFuncSetAttribute((const void*)rnn_fallback_kernel,
                              hipFuncAttributeMaxDynamicSharedMemorySize, FB_SMEM);
    rnn_fallback_kernel<<<dim3(NBLK), dim3(512), FB_SMEM, stream>>>(
        x, Whx, Whh, Wph, bh, bp, out);
  }
}

// Round 9
// 1887.075 us; speedup vs baseline: 1.5981x; 1.5981x over previous
//
#include <hip/hip_runtime.h>
#include <hip/hip_bf16.h>
#include <hip/hip_fp8.h>
#include <cstdint>
#include <cstddef>

// VanillaRNN: h_{t+1} = tanh(x_t @ Whx + h_t @ Whh + bh), p = h_T @ Wph + bp
// B=256, T=1024, D=64, H=512, C=10.
//
// R8 vs R7 (R6 fused 2747us, R7 fused 3016us — both fused variants are
// 800-1300us slower than the serial consumer even though producers finish in
// the first ~150us; gate-cost theory falsified by R7. REVERT to best measured
// structure):
//  - Serial two-launch. Consumer = R3-exact kernel (measured 1693us/dispatch):
//    KS 10/2/4 split, C || C2 chains, fold at epilogue, U full t in [0,1024).
//  - Precompute rebuilt for BW-bound operation: TT=64, grid (16,16) = 256
//    blocks = exactly 1 block/CU. Weight preload paid ONCE per block (was
//    1024-2048x), x(t+1) software-prefetched inside the 64-step loop.
//    BW floor: 268MB U-write + 67MB x-read ~= 55us (was ~200us).
// Fallback (ws < 256MiB): R2 kernel verbatim (2833us).

#define T_SEQ   1024
#define D_IN    64
#define H_DIM   512
#define NB      16
#define NBLK    16
#define NTW     4            // N-tiles (16 cols) per wave; wave owns 64 cols
#define KS_F16  10           // f16 K-steps: h[0,320)  (R3 split)
#define KS_REG8 2            // fp8 K-steps with reg weights: h[320,384)
#define KS_LDS8 4            // fp8 K-steps with LDS weights: h[384,512)
#define HSPLIT  320          // h cols >= HSPLIT stored fp8
#define APITCH  848          // bytes per A row: 640 f16 + 192 fp8 + 16 pad
#define FP8OFF  640
#define ABUF_BYTES (2 * NB * APITCH)              // 27136
#define WWAVE_BYTES (KS_LDS8 * 2 * 1024)          // 8192
#define WLDS_BYTES (8 * WWAVE_BYTES)              // 65536
#define SMEM_TOTAL (ABUF_BYTES + WLDS_BYTES)      // 92672
#define WSCALE  256.0f
#define HSCALE  128.0f
#define UNSCALE (1.0f / 32768.0f)
#define U_BYTES ((size_t)T_SEQ * NBLK * 512 * 32) // 268435456 (f16 U, all t)
#define TTP     64           // t-steps per precompute block (grid 16x16)

typedef __attribute__((ext_vector_type(8))) short  short8;
typedef __attribute__((ext_vector_type(4))) short  short4v;
typedef __attribute__((ext_vector_type(4))) float  f32x4;
typedef __attribute__((ext_vector_type(4))) unsigned int uint4v;
typedef __attribute__((ext_vector_type(2))) unsigned int uint2v;

static __device__ __forceinline__ short f16b(float v) {
  return __builtin_bit_cast(short, (_Float16)v);
}
static __device__ __forceinline__ short bf16b(float v) {
  return __builtin_bit_cast(short, __float2bfloat16(v));
}
static __device__ __forceinline__ float f16f(unsigned short u) {
  return (float)__builtin_bit_cast(_Float16, (short)u);
}
static __device__ __forceinline__ unsigned int pk2h(float a, float b) {
#if defined(__has_builtin) && __has_builtin(__builtin_amdgcn_cvt_pkrtz)
  return __builtin_bit_cast(unsigned int, __builtin_amdgcn_cvt_pkrtz(a, b));
#else
  return (unsigned int)(unsigned short)f16b(a) |
         ((unsigned int)(unsigned short)f16b(b) << 16);
#endif
}
static __device__ __forceinline__ float fast_tanh(float x) {
  x = fminf(20.f, fmaxf(-20.f, x));
  const float t = __builtin_amdgcn_exp2f(x * 2.885390081777927f); // 2*log2(e)
  return (t - 1.f) * __builtin_amdgcn_rcpf(t + 1.f);
}
static __device__ __forceinline__ unsigned char f32_to_fp8(float v) {
#if defined(__has_builtin) && __has_builtin(__builtin_amdgcn_cvt_pk_fp8_f32)
  const int r = __builtin_amdgcn_cvt_pk_fp8_f32(v, v, 0, false);
  return (unsigned char)(r & 0xff);
#else
  __hip_fp8_e4m3 f(v);
  return (unsigned char)f.__x;
#endif
}
static __device__ __forceinline__ unsigned int pk4fp8(float a, float b, float c, float d) {
#if defined(__has_builtin) && __has_builtin(__builtin_amdgcn_cvt_pk_fp8_f32)
  int r = __builtin_amdgcn_cvt_pk_fp8_f32(a, b, 0, false);
  r = __builtin_amdgcn_cvt_pk_fp8_f32(c, d, r, true);
  return (unsigned int)r;
#else
  return (unsigned int)f32_to_fp8(a) | ((unsigned int)f32_to_fp8(b) << 8) |
         ((unsigned int)f32_to_fp8(c) << 16) | ((unsigned int)f32_to_fp8(d) << 24);
#endif
}
static __device__ __forceinline__ float fp8_to_f32(unsigned char b) {
  __hip_fp8_e4m3 f;
  f.__x = (__hip_fp8_storage_t)b;
  return (float)f;
}

// ============================ precompute: U = x@Whx + bh =====================
// U slot: thread (wg, tid) at step t owns 32 B at ((t*NBLK+wg)*512+tid)*32.
// Grid (NBLK, 16): block = (wg, 64-step chunk); 256 blocks = 1/CU. Weights
// preloaded once; x(t+1) prefetched so the loop runs at store-BW.
__global__ __launch_bounds__(512, 2)
void rnn_u_precompute(const float* __restrict__ x, const float* __restrict__ Whx,
                      const float* __restrict__ bh, char* __restrict__ U)
{
  const int tid  = threadIdx.x;
  const int lane = tid & 63;
  const int w    = tid >> 6;
  const int n16  = lane & 15;
  const int kq   = lane >> 4;
  const int wg   = blockIdx.x;
  const int cwave = w * 64;

  // A-operand frags: Whx^T. lane m=n16 -> col c; holds Whx[k0+kq*8+j][c].
  short8 wa[2][NTW];
  #pragma unroll
  for (int s = 0; s < 2; ++s) {
    #pragma unroll
    for (int nt = 0; nt < NTW; ++nt) {
      const int c = cwave + nt * 16 + n16;
      short8 f;
      #pragma unroll
      for (int j = 0; j < 8; ++j)
        f[j] = f16b(Whx[(size_t)(s * 32 + kq * 8 + j) * H_DIM + c]);
      wa[s][nt] = f;
    }
  }
  f32x4 bb[NTW];
  #pragma unroll
  for (int nt = 0; nt < NTW; ++nt) {
    #pragma unroll
    for (int i = 0; i < 4; ++i) bb[nt][i] = bh[cwave + nt * 16 + kq * 4 + i];
  }

  const int b = wg * NB + n16;
  const float* pxb = x + (size_t)b * T_SEQ * D_IN + kq * 8;
  const int t0 = blockIdx.y * TTP;

  // x regs for current step (double-buffered against next)
  f32x4 c0, c1, c2, c3;
  {
    const float* p = pxb + (size_t)t0 * D_IN;
    c0 = *(const f32x4*)p;        c1 = *(const f32x4*)(p + 4);
    c2 = *(const f32x4*)(p + 32); c3 = *(const f32x4*)(p + 36);
  }

  for (int tt = 0; tt < TTP; ++tt) {
    const int t = t0 + tt;
    f32x4 n0, n1, n2, n3;
    if (tt + 1 < TTP) {
      const float* p = pxb + (size_t)(t + 1) * D_IN;
      n0 = *(const f32x4*)p;        n1 = *(const f32x4*)(p + 4);
      n2 = *(const f32x4*)(p + 32); n3 = *(const f32x4*)(p + 36);
    }
    short8 xb0, xb1;
    xb0[0]=f16b(c0.x); xb0[1]=f16b(c0.y); xb0[2]=f16b(c0.z); xb0[3]=f16b(c0.w);
    xb0[4]=f16b(c1.x); xb0[5]=f16b(c1.y); xb0[6]=f16b(c1.z); xb0[7]=f16b(c1.w);
    xb1[0]=f16b(c2.x); xb1[1]=f16b(c2.y); xb1[2]=f16b(c2.z); xb1[3]=f16b(c2.w);
    xb1[4]=f16b(c3.x); xb1[5]=f16b(c3.y); xb1[6]=f16b(c3.z); xb1[7]=f16b(c3.w);

    f32x4 D[NTW];
    #pragma unroll
    for (int nt = 0; nt < NTW; ++nt) {
      D[nt] = bb[nt];
      D[nt] = __builtin_amdgcn_mfma_f32_16x16x32_f16(wa[0][nt], xb0, D[nt], 0, 0, 0);
      D[nt] = __builtin_amdgcn_mfma_f32_16x16x32_f16(wa[1][nt], xb1, D[nt], 0, 0, 0);
    }
    uint4v o0, o1;
    o0.x = pk2h(D[0][0], D[0][1]); o0.y = pk2h(D[0][2], D[0][3]);
    o0.z = pk2h(D[1][0], D[1][1]); o0.w = pk2h(D[1][2], D[1][3]);
    o1.x = pk2h(D[2][0], D[2][1]); o1.y = pk2h(D[2][2], D[2][3]);
    o1.z = pk2h(D[3][0], D[3][1]); o1.w = pk2h(D[3][2], D[3][3]);
    char* dst = U + (((size_t)t * NBLK + wg) * 512 + tid) * 32;
    *(uint4v*)dst = o0;
    *(uint4v*)(dst + 16) = o1;

    c0 = n0; c1 = n1; c2 = n2; c3 = n3;
  }
}

// ============================ main recurrence (R3-exact, 1693us) =============
__global__ __launch_bounds__(512, 2)
void VanillaRNN_70025146794452_kernel(
    const float* __restrict__ Whh,  // [512][512]
    const float* __restrict__ Wph,  // [512][10]
    const float* __restrict__ bp,   // [10]
    const char* __restrict__ U,     // precomputed, swizzled f16
    float* __restrict__ out)        // [256][10]
{
  const int tid  = threadIdx.x;
  const int lane = tid & 63;
  const int w    = tid >> 6;
  const int n16  = lane & 15;
  const int kq   = lane >> 4;
  const int rbase = blockIdx.x * NB;
  const int cwave = w * 64;

  extern __shared__ char smem[];
  char* Ab  = smem;                                  // [2][NB][APITCH]
  char* Wlw = smem + ABUF_BYTES + w * WWAVE_BYTES;   // this wave's LDS fp8 wts

  // -------- preload: f16 weight A-frags (h-k in [0,320)), 40 frags
  short8 wr[KS_F16][NTW];
  #pragma unroll
  for (int s = 0; s < KS_F16; ++s) {
    #pragma unroll
    for (int nt = 0; nt < NTW; ++nt) {
      const int c = cwave + nt * 16 + n16;
      short8 f;
      #pragma unroll
      for (int j = 0; j < 8; ++j)
        f[j] = f16b(Whh[(size_t)(s * 32 + kq * 8 + j) * H_DIM + c]);
      wr[s][nt] = f;
    }
  }
  // -------- preload: reg-resident fp8 weight A-frags (h-k in [320,384))
  long long wf8[KS_REG8][NTW];
  #pragma unroll
  for (int s = 0; s < KS_REG8; ++s) {
    #pragma unroll
    for (int nt = 0; nt < NTW; ++nt) {
      const int c  = cwave + nt * 16 + n16;
      const int k0 = (KS_F16 + s) * 32 + kq * 8;
      unsigned int lo = 0, hi = 0;
      #pragma unroll
      for (int bi = 0; bi < 4; ++bi) {
        lo |= ((unsigned int)f32_to_fp8(Whh[(size_t)(k0 + bi) * H_DIM + c] * WSCALE)) << (8 * bi);
        hi |= ((unsigned int)f32_to_fp8(Whh[(size_t)(k0 + 4 + bi) * H_DIM + c] * WSCALE)) << (8 * bi);
      }
      wf8[s][nt] = (long long)(((unsigned long long)hi << 32) | lo);
    }
  }
  // -------- preload: LDS fp8 weight A-frags (h-k in [384,512))
  for (int sl = 0; sl < KS_LDS8; ++sl) {
    for (int half = 0; half < 2; ++half) {
      const int k0 = (KS_F16 + KS_REG8 + sl) * 32 + kq * 8;
      unsigned int bqq[4];
      #pragma unroll
      for (int hh = 0; hh < 2; ++hh) {
        const int c = cwave + (2 * half + hh) * 16 + n16;
        #pragma unroll
        for (int u = 0; u < 2; ++u) {
          unsigned int acc = 0;
          #pragma unroll
          for (int bi = 0; bi < 4; ++bi)
            acc |= ((unsigned int)f32_to_fp8(Whh[(size_t)(k0 + u * 4 + bi) * H_DIM + c] * WSCALE)) << (8 * bi);
          bqq[hh * 2 + u] = acc;
        }
      }
      uint4v pk; pk.x = bqq[0]; pk.y = bqq[1]; pk.z = bqq[2]; pk.w = bqq[3];
      *(uint4v*)(Wlw + (size_t)(sl * 2 + half) * 1024 + lane * 16) = pk;
    }
  }

  // -------- prologue: zero both A buffers (h_0 = 0), prefetch U(t=0)
  for (int i = tid; i < ABUF_BYTES / 4; i += 512) ((int*)Ab)[i] = 0;
  uint4v Upf0, Upf1;
  {
    const char* up = U + (((size_t)0 * NBLK + blockIdx.x) * 512 + tid) * 32;
    Upf0 = *(const uint4v*)up;
    Upf1 = *(const uint4v*)(up + 16);
  }

  f32x4 C[NTW], C2[NTW];

  // -------- main recurrence (C || C2 chains, fold at epilogue)
  for (int t = 0; t < T_SEQ; ++t) {
    __syncthreads();
    char* Ac = Ab + (t & 1) * (NB * APITCH);
    char* An = Ab + ((t + 1) & 1) * (NB * APITCH);

    short8 hb = *(const short8*)(Ac + n16 * APITCH + 0 * 64 + kq * 16);

    // C-init from prefetched U
    C[0][0]=f16f(Upf0.x&0xffff); C[0][1]=f16f(Upf0.x>>16);
    C[0][2]=f16f(Upf0.y&0xffff); C[0][3]=f16f(Upf0.y>>16);
    C[1][0]=f16f(Upf0.z&0xffff); C[1][1]=f16f(Upf0.z>>16);
    C[1][2]=f16f(Upf0.w&0xffff); C[1][3]=f16f(Upf0.w>>16);
    C[2][0]=f16f(Upf1.x&0xffff); C[2][1]=f16f(Upf1.x>>16);
    C[2][2]=f16f(Upf1.y&0xffff); C[2][3]=f16f(Upf1.y>>16);
    C[3][0]=f16f(Upf1.z&0xffff); C[3][1]=f16f(Upf1.z>>16);
    C[3][2]=f16f(Upf1.w&0xffff); C[3][3]=f16f(Upf1.w>>16);
    #pragma unroll
    for (int nt = 0; nt < NTW; ++nt) C2[nt] = (f32x4){0.f, 0.f, 0.f, 0.f};

    // prefetch U(t+1)
    {
      const int t1 = (t + 1 < T_SEQ) ? (t + 1) : (T_SEQ - 1);
      const char* up = U + (((size_t)t1 * NBLK + blockIdx.x) * 512 + tid) * 32;
      Upf0 = *(const uint4v*)up;
      Upf1 = *(const uint4v*)(up + 16);
    }

    // f16 phase (C-chain)
    #pragma unroll
    for (int s = 0; s < KS_F16; ++s) {
      const short8 a = hb;
      if (s + 1 < KS_F16)
        hb = *(const short8*)(Ac + n16 * APITCH + (s + 1) * 64 + kq * 16);
      #pragma unroll
      for (int nt = 0; nt < NTW; ++nt)
        C[nt] = __builtin_amdgcn_mfma_f32_16x16x32_f16(wr[s][nt], a, C[nt], 0, 0, 0);
    }
    // fp8 phase (independent C2-chain)
    #pragma unroll
    for (int s = 0; s < KS_REG8; ++s) {
      const long long h8 = *(const long long*)(Ac + n16 * APITCH + FP8OFF + s * 32 + kq * 8);
      #pragma unroll
      for (int nt = 0; nt < NTW; ++nt)
        C2[nt] = __builtin_amdgcn_mfma_f32_16x16x32_fp8_fp8(wf8[s][nt], h8, C2[nt], 0, 0, 0);
    }
    #pragma unroll
    for (int sl = 0; sl < KS_LDS8; ++sl) {
      const long long h8 = *(const long long*)(Ac + n16 * APITCH + FP8OFF + (KS_REG8 + sl) * 32 + kq * 8);
      const uint4v q0 = *(const uint4v*)(Wlw + (size_t)(sl * 2 + 0) * 1024 + lane * 16);
      const uint4v q1 = *(const uint4v*)(Wlw + (size_t)(sl * 2 + 1) * 1024 + lane * 16);
      const long long w0 = (long long)(((unsigned long long)q0.y << 32) | q0.x);
      const long long w1 = (long long)(((unsigned long long)q0.w << 32) | q0.z);
      const long long w2 = (long long)(((unsigned long long)q1.y << 32) | q1.x);
      const long long w3 = (long long)(((unsigned long long)q1.w << 32) | q1.z);
      C2[0] = __builtin_amdgcn_mfma_f32_16x16x32_fp8_fp8(w0, h8, C2[0], 0, 0, 0);
      C2[1] = __builtin_amdgcn_mfma_f32_16x16x32_fp8_fp8(w1, h8, C2[1], 0, 0, 0);
      C2[2] = __builtin_amdgcn_mfma_f32_16x16x32_fp8_fp8(w2, h8, C2[2], 0, 0, 0);
      C2[3] = __builtin_amdgcn_mfma_f32_16x16x32_fp8_fp8(w3, h8, C2[3], 0, 0, 0);
    }

    // epilogue: fold + tanh + packed store (D transposed: row n16 = batch,
    // reg i = col kq*4+i)
    char* drow = An + n16 * APITCH;
    if (cwave < HSPLIT) {            // waves 0..4: f16 region
      #pragma unroll
      for (int nt = 0; nt < NTW; ++nt) {
        const int c0 = cwave + nt * 16 + kq * 4;
        float v0 = fast_tanh(fmaf(C2[nt][0], UNSCALE, C[nt][0]));
        float v1 = fast_tanh(fmaf(C2[nt][1], UNSCALE, C[nt][1]));
        float v2 = fast_tanh(fmaf(C2[nt][2], UNSCALE, C[nt][2]));
        float v3 = fast_tanh(fmaf(C2[nt][3], UNSCALE, C[nt][3]));
        uint2v o; o.x = pk2h(v0, v1); o.y = pk2h(v2, v3);
        *(uint2v*)(drow + c0 * 2) = o;
      }
    } else {                          // waves 5..7: fp8 region
      #pragma unroll
      for (int nt = 0; nt < NTW; ++nt) {
        const int c0 = cwave + nt * 16 + kq * 4;
        float v0 = fast_tanh(fmaf(C2[nt][0], UNSCALE, C[nt][0]));
        float v1 = fast_tanh(fmaf(C2[nt][1], UNSCALE, C[nt][1]));
        float v2 = fast_tanh(fmaf(C2[nt][2], UNSCALE, C[nt][2]));
        float v3 = fast_tanh(fmaf(C2[nt][3], UNSCALE, C[nt][3]));
        *(unsigned int*)(drow + FP8OFF + (c0 - HSPLIT)) =
            pk4fp8(v0 * HSCALE, v1 * HSCALE, v2 * HSCALE, v3 * HSCALE);
      }
    }
  }

  __syncthreads();
  // h_T in buffer 0 (T even). Projection: 16 rows x 10 classes per block.
  if (tid < NB * 10) {
    const int r = tid / 10, c = tid % 10;
    const char* row = Ab + r * APITCH;
    float acc = bp[c];
    #pragma unroll 8
    for (int k = 0; k < HSPLIT; ++k)
      acc += f16f(*(const unsigned short*)(row + k * 2)) * Wph[k * 10 + c];
    #pragma unroll 8
    for (int k = HSPLIT; k < H_DIM; ++k)
      acc += fp8_to_f32((unsigned char)row[FP8OFF + (k - HSPLIT)]) * (1.f / HSCALE) * Wph[k * 10 + c];
    out[(size_t)(rbase + r) * 10 + c] = acc;
  }
}

// ============================ fallback (R2 verbatim, 2833us) =================
#define FB_APITCH  1040
#define FB_FP8OFF  768
#define FB_ABUF    (2 * NB * FB_APITCH)
#define FB_WWAVE   (6 * 2 * 1024)
#define FB_SMEM    (FB_ABUF + 8 * FB_WWAVE)       // 131584

__global__ __launch_bounds__(512, 2)
void rnn_fallback_kernel(
    const float* __restrict__ x, const float* __restrict__ Whx,
    const float* __restrict__ Whh, const float* __restrict__ Wph,
    const float* __restrict__ bh, const float* __restrict__ bp,
    float* __restrict__ out)
{
  const int tid = threadIdx.x, lane = tid & 63, w = tid >> 6;
  const int n16 = lane & 15, kq = lane >> 4;
  const int rbase = blockIdx.x * NB, cwave = w * 64;
  extern __shared__ char smem[];
  char* Ab  = smem;
  char* Wlw = smem + FB_ABUF + w * FB_WWAVE;

  short8 wr[12 * 4];
  #pragma unroll
  for (int s = 0; s < 12; ++s)
    #pragma unroll
    for (int nt = 0; nt < 4; ++nt) {
      const int c = cwave + nt * 16 + n16, k0 = s * 32 + kq * 8;
      short8 f;
      #pragma unroll
      for (int j = 0; j < 8; ++j) {
        const int k = k0 + j;
        const float* src = (k < D_IN) ? (Whx + (size_t)k * H_DIM + c)
                                      : (Whh + (size_t)(k - D_IN) * H_DIM + c);
        f[j] = bf16b(*src);
      }
      wr[s * 4 + nt] = f;
    }
  for (int s = 0; s < 6; ++s)
    for (int pp = 0; pp < 2; ++pp) {
      const int k0 = (12 + s) * 32 + kq * 8;
      unsigned int bq[4];
      #pragma unroll
      for (int half = 0; half < 2; ++half) {
        const int c = cwave + (2 * pp + half) * 16 + n16;
        #pragma unroll
        for (int u = 0; u < 2; ++u) {
          unsigned int acc = 0;
          #pragma unroll
          for (int bi = 0; bi < 4; ++bi)
            acc |= ((unsigned int)f32_to_fp8(Whh[(size_t)(k0 + u * 4 + bi - D_IN) * H_DIM + c] * WSCALE)) << (8 * bi);
          bq[half * 2 + u] = acc;
        }
      }
      uint4v pk; pk.x = bq[0]; pk.y = bq[1]; pk.z = bq[2]; pk.w = bq[3];
      *(uint4v*)(Wlw + (size_t)(s * 2 + pp) * 1024 + lane * 16) = pk;
    }
  float bhreg[4];
  #pragma unroll
  for (int nt = 0; nt < 4; ++nt) bhreg[nt] = bh[cwave + nt * 16 + n16];
  for (int i = tid; i < FB_ABUF / 4; i += 512) ((int*)Ab)[i] = 0;
  const int xr = (tid >> 4) & 15, xc4 = (tid & 15) * 4;
  if (tid < 256) {
    const f32x4 xv = *(const f32x4*)(x + ((size_t)(rbase + xr) * T_SEQ) * D_IN + xc4);
    short4v s4; s4[0]=bf16b(xv.x); s4[1]=bf16b(xv.y); s4[2]=bf16b(xv.z); s4[3]=bf16b(xv.w);
    *(short4v*)(Ab + xr * FB_APITCH + xc4 * 2) = s4;
  }
  f32x4 C[4], C2[4];
  for (int t = 0; t < T_SEQ; ++t) {
    __syncthreads();
    char* Ac = Ab + (t & 1) * (NB * FB_APITCH);
    char* An = Ab + ((t + 1) & 1) * (NB * FB_APITCH);
    const int t1 = (t + 1 < T_SEQ) ? (t + 1) : (T_SEQ - 1);
    f32x4 xv;
    if (tid < 256)
      xv = *(const f32x4*)(x + ((size_t)(rbase + xr) * T_SEQ + t1) * D_IN + xc4);
    #pragma unroll
    for (int nt = 0; nt < 4; ++nt) {
      C[nt] = (f32x4){0.f,0.f,0.f,0.f}; C2[nt] = (f32x4){0.f,0.f,0.f,0.f};
    }
    #pragma unroll
    for (int s = 0; s < 12; ++s) {
      const short8 a = *(const short8*)(Ac + n16 * FB_APITCH + s * 64 + kq * 16);
      #pragma unroll
      for (int nt = 0; nt < 4; ++nt)
        C[nt] = __builtin_amdgcn_mfma_f32_16x16x32_bf16(a, wr[s * 4 + nt], C[nt], 0, 0, 0);
    }
    #pragma unroll
    for (int s = 0; s < 6; ++s) {
      const long long a8 = *(const long long*)(Ac + n16 * FB_APITCH + FB_FP8OFF + s * 32 + kq * 8);
      #pragma unroll
      for (int pp = 0; pp < 2; ++pp) {
        const uint4v q = *(const uint4v*)(Wlw + (size_t)(s * 2 + pp) * 1024 + lane * 16);
        const long long b0 = (long long)(((unsigned long long)q.y << 32) | q.x);
        const long long b1 = (long long)(((unsigned long long)q.w << 32) | q.z);
        C2[2*pp]   = __builtin_amdgcn_mfma_f32_16x16x32_fp8_fp8(a8, b0, C2[2*pp],   0, 0, 0);
        C2[2*pp+1] = __builtin_amdgcn_mfma_f32_16x16x32_fp8_fp8(a8, b1, C2[2*pp+1], 0, 0, 0);
      }
    }
    if (tid < 256) {
      short4v s4; s4[0]=bf16b(xv.x); s4[1]=bf16b(xv.y); s4[2]=bf16b(xv.z); s4[3]=bf16b(xv.w);
      *(short4v*)(An + xr * FB_APITCH + xc4 * 2) = s4;
    }
    const int row0 = kq * 4;
    #pragma unroll
    for (int nt = 0; nt < 4; ++nt) {
      const int cbase = cwave + nt * 16;
      #pragma unroll
      for (int i = 0; i < 4; ++i) {
        const float v = fast_tanh(fmaf(C2[nt][i], UNSCALE, C[nt][i]) + bhreg[nt]);
        char* dst = An + (row0 + i) * FB_APITCH;
        if (cbase < 320) *(short*)(dst + 128 + (cbase + n16) * 2) = bf16b(v);
        else dst[FB_FP8OFF + (cbase + n16 - 320)] = f32_to_fp8(v * HSCALE);
      }
    }
  }
  __syncthreads();
  if (tid < NB * 10) {
    const int r = tid / 10, c = tid % 10;
    const char* row = Ab + r * FB_APITCH;
    float acc = bp[c];
    #pragma unroll 8
    for (int k = 0; k < 320; ++k) {
      const __hip_bfloat16 hb = __builtin_bit_cast(__hip_bfloat16, *(const short*)(row + 128 + k * 2));
      acc += __bfloat162float(hb) * Wph[k * 10 + c];
    }
    #pragma unroll 8
    for (int k = 320; k < H_DIM; ++k)
      acc += fp8_to_f32((unsigned char)row[FB_FP8OFF + (k - 320)]) * (1.f / HSCALE) * Wph[k * 10 + c];
    out[(size_t)(rbase + r) * 10 + c] = acc;
  }
}

extern "C" void kernel_launch(void* const* d_in, const int* in_sizes, int n_in,
                              void* d_out, int out_size, void* d_ws, size_t ws_size,
                              hipStream_t stream) {
  const float* x   = (const float*)d_in[0];
  const float* Whx = (const float*)d_in[1];
  const float* Whh = (const float*)d_in[2];
  const float* Wph = (const float*)d_in[3];
  const float* bh  = (const float*)d_in[4];
  const float* bp  = (const float*)d_in[5];
  float* out = (float*)d_out;

  if (ws_size >= U_BYTES) {
    char* U = (char*)d_ws;
    (void)hipFuncSetAttribute((const void*)VanillaRNN_70025146794452_kernel,
                              hipFuncAttributeMaxDynamicSharedMemorySize, SMEM_TOTAL);
    rnn_u_precompute<<<dim3(NBLK, T_SEQ / TTP), dim3(512), 0, stream>>>(x, Whx, bh, U);
    VanillaRNN_70025146794452_kernel<<<dim3(NBLK), dim3(512), SMEM_TOTAL, stream>>>(
        Whh, Wph, bp, U, out);
  } else {
    (void)hipFuncSetAttribute((const void*)rnn_fallback_kernel,
                              hipFuncAttributeMaxDynamicSharedMemorySize, FB_SMEM);
    rnn_fallback_kernel<<<dim3(NBLK), dim3(512), FB_SMEM, stream>>>(
        x, Whx, Whh, Wph, bh, bp, out);
  }
}